// Round 9
// baseline (282.530 us; speedup 1.0000x reference)
//
#include <hip/hip_runtime.h>
#include <stdint.h>

typedef _Float16 f16;
typedef f16 half8 __attribute__((ext_vector_type(8)));
typedef f16 half4 __attribute__((ext_vector_type(4)));
typedef float floatx4 __attribute__((ext_vector_type(4)));

#define MFMA_F16(A, B, Cc) __builtin_amdgcn_mfma_f32_16x16x32_f16((A), (B), (Cc), 0, 0, 0)

// Problem constants: B=4, H=W=64 -> N=4096, C=256, d=32
static constexpr int NB  = 4;
static constexpr int NN  = 4096;
static constexpr int NC  = 256;
static constexpr int ND  = 32;
static constexpr int PIX = NB * NN;   // 16384
static constexpr int NS  = 4;         // key splits (grid 512 = 2 blocks/CU, reg-capped)
static constexpr int KS  = NN / NS;   // 1024 keys per split
static constexpr int NT  = NB * (NN / 128);  // 128 q-tiles (merge units)

// Device-global scratch. Fully rewritten every launch.
__device__ __align__(16) f16 g_Xh[(size_t)PIX * NC];        // x as f16 (written by proj)
__device__ __align__(16) f16 g_WbT[320 * 256];              // [j][k]
__device__ __align__(16) f16 g_Qh[(size_t)PIX * ND];        // [row][32], pre-scaled log2(e)
__device__ __align__(16) f16 g_Kh[(size_t)PIX * ND];        // [row][32]
__device__ __align__(16) f16 g_VbT[(size_t)NB * NC * NN];   // [b][c][n]
__device__ __align__(16) f16 g_Of[(size_t)NS * PIX * NC];   // per-split normalized O
__device__ float g_m[NS * PIX];                             // per-split max (log2 dom)
__device__ float g_l[NS * PIX];                             // per-split denom
__device__ int   g_cnt[NT];                                 // per-tile arrival counter

__device__ inline void gl2lds16(const f16* g, f16* l) {
  __builtin_amdgcn_global_load_lds(
      (const __attribute__((address_space(1))) void*)g,
      (__attribute__((address_space(3))) void*)l, 16, 0, 0);
}

// ---------------------------------------------------------------------------
// prep_weights: fp32 -> f16 transposed weights; also zeroes merge counters
// (required every launch: harness re-poisons device scratch semantics).
__global__ __launch_bounds__(256) void prep_weights(const float* __restrict__ wq,
                                                    const float* __restrict__ wk,
                                                    const float* __restrict__ wv) {
  if (blockIdx.x == 0 && threadIdx.x < NT) g_cnt[threadIdx.x] = 0;
  const int tid = blockIdx.x * 256 + threadIdx.x;
  if (tid >= 320 * 256) return;
  const int j = tid >> 8;
  const int k = tid & 255;
  float v;
  if (j < 32)      v = wq[k * 32 + j];
  else if (j < 64) v = wk[k * 32 + (j - 32)];
  else             v = wv[k * 256 + (j - 64)];
  g_WbT[j * 256 + k] = (f16)v;
}

// ---------------------------------------------------------------------------
// QKV projection (round-6 monolithic form) + writes g_Xh as a side product
// (x fp32 read once; f16 copy feeds the fused residual in attn's merge).
__global__ __launch_bounds__(256) void proj_qkv(const float* __restrict__ x,
                                                const float* __restrict__ bq,
                                                const float* __restrict__ bk,
                                                const float* __restrict__ bv) {
  __shared__ f16 xs[64 * 32];    // 4 KB
  __shared__ f16 wsT[320 * 32];  // 20 KB
  __shared__ f16 vt[256 * 64];   // 32 KB

  const int tid  = threadIdx.x;
  const int lane = tid & 63;
  const int wid  = tid >> 6;
  const int qd   = lane >> 4;
  const int c16  = lane & 15;
  const int p0   = blockIdx.x * 64;
  const floatx4 zero4 = {0.f, 0.f, 0.f, 0.f};

  floatx4 acc[20];
#pragma unroll
  for (int i = 0; i < 20; ++i) acc[i] = zero4;

  for (int kk = 0; kk < 256; kk += 32) {
    {
      const int r = tid >> 2, g = tid & 3;
      const floatx4* s4 = (const floatx4*)(x + (size_t)(p0 + r) * NC + kk + g * 8);
      const floatx4 xa = s4[0], xb = s4[1];
      half8 h;
      h[0] = (f16)xa[0]; h[1] = (f16)xa[1]; h[2] = (f16)xa[2]; h[3] = (f16)xa[3];
      h[4] = (f16)xb[0]; h[5] = (f16)xb[1]; h[6] = (f16)xb[2]; h[7] = (f16)xb[3];
      *(half8*)&xs[r * 32 + g * 8] = h;
      *(half8*)&g_Xh[(size_t)(p0 + r) * NC + kk + g * 8] = h;  // side product
    }
#pragma unroll
    for (int i = 0; i < 10; ++i) {
      const int cid = tid + 256 * i;
      const int j = cid >> 3, m = cid & 7;
      *(half4*)&wsT[j * 32 + m * 4] = *(const half4*)&g_WbT[j * 256 + kk + m * 4];
    }
    __syncthreads();
    const half8 a = *(const half8*)&xs[(wid * 16 + c16) * 32 + qd * 8];
#pragma unroll
    for (int nt = 0; nt < 20; ++nt) {
      const half8 bfr = *(const half8*)&wsT[(nt * 16 + c16) * 32 + qd * 8];
      acc[nt] = MFMA_F16(a, bfr, acc[nt]);
    }
    __syncthreads();
  }

#pragma unroll
  for (int nt = 0; nt < 20; ++nt) {
    const int j = nt * 16 + c16;
    const float bias = (j < 32) ? bq[j] : (j < 64) ? bk[j - 32] : bv[j - 64];
#pragma unroll
    for (int r = 0; r < 4; ++r) {
      const int rl = wid * 16 + qd * 4 + r;
      const int p  = p0 + rl;
      const float val = acc[nt][r] + bias;
      if (j < 32) {
        g_Qh[(size_t)p * ND + j] = (f16)(val * 1.44269504f);  // log2(e)
      } else if (j < 64) {
        g_Kh[(size_t)p * ND + (j - 32)] = (f16)val;
      } else {
        vt[(j - 64) * 64 + rl] = (f16)val;
      }
    }
  }
  __syncthreads();
  const int b  = p0 >> 12;
  const int n0 = p0 & (NN - 1);
#pragma unroll
  for (int i = 0; i < 16; ++i) {
    const int cid = tid + 256 * i;
    const int c = cid >> 4, m = cid & 15;
    *(half4*)(g_VbT + ((size_t)(b * NC + c)) * NN + n0 + m * 4) =
        *(const half4*)&vt[c * 64 + m * 4];
  }
}

// ---------------------------------------------------------------------------
// Flash attention (round-6 core, 70 µs measured) + fused last-block merge.
// Block = 128 q (4 waves x 32 q), K-tile = 64 keys, blockIdx.z = 1024-key
// split. K direct-from-global regs; V async gl2lds, XOR-chunk-swizzled.
__global__ __launch_bounds__(256, 2) void attn_split(float* __restrict__ out) {
  __shared__ f16 vsT[256 * 64];        // 32 KB [c][64 keys], chunk-swizzled
  __shared__ f16 ps[4][2][16 * 64];    // 16 KB [wave][qgrp][q][64 keys], swizzled
  __shared__ int s_last;

  const int tid  = threadIdx.x;
  const int lane = tid & 63;
  const int wid  = tid >> 6;
  const int qd   = lane >> 4;
  const int c16  = lane & 15;
  const int b    = blockIdx.y;
  const int s    = blockIdx.z;
  const int q0   = blockIdx.x * 128 + wid * 32;
  const int sx7  = c16 & 7;
  const floatx4 zero4 = {0.f, 0.f, 0.f, 0.f};

  const int vrow = wid * 64 + (lane >> 3);
  const int vchk = (lane & 7) ^ ((lane >> 3) & 7);
  const f16* vlane = g_VbT + ((size_t)(b * NC + vrow)) * NN + vchk * 8;
  f16* vdst = &vsT[(size_t)wid * 4096];

  half8 qf[2];
#pragma unroll
  for (int g = 0; g < 2; ++g)
    qf[g] = *(const half8*)(g_Qh + ((size_t)(b * NN + q0 + g * 16 + c16)) * ND + qd * 8);

  floatx4 acc[2][16];
#pragma unroll
  for (int g = 0; g < 2; ++g)
#pragma unroll
    for (int i = 0; i < 16; ++i) acc[g][i] = zero4;
  float m_i[2] = {-1e30f, -1e30f};
  float l_p[2] = {0.f, 0.f};

  const int kbeg = s * KS, kend = (s + 1) * KS;

#pragma unroll
  for (int i = 0; i < 8; ++i)
    gl2lds16(vlane + kbeg + i * 8 * NN, vdst + i * 512);
  half8 kreg[4];
#pragma unroll
  for (int a = 0; a < 4; ++a)
    kreg[a] = *(const half8*)(g_Kh + ((size_t)(b * NN + kbeg + a * 16 + c16)) * ND + qd * 8);

  for (int k0 = kbeg; k0 < kend; k0 += 64) {
    floatx4 st[2][4];
#pragma unroll
    for (int g = 0; g < 2; ++g)
#pragma unroll
      for (int a = 0; a < 4; ++a) st[g][a] = MFMA_F16(kreg[a], qf[g], zero4);

    float tm[2];
#pragma unroll
    for (int g = 0; g < 2; ++g) {
      float t0 = fmaxf(fmaxf(st[g][0][0], st[g][0][1]), fmaxf(st[g][0][2], st[g][0][3]));
      float t1 = fmaxf(fmaxf(st[g][1][0], st[g][1][1]), fmaxf(st[g][1][2], st[g][1][3]));
      float t2 = fmaxf(fmaxf(st[g][2][0], st[g][2][1]), fmaxf(st[g][2][2], st[g][2][3]));
      float t3 = fmaxf(fmaxf(st[g][3][0], st[g][3][1]), fmaxf(st[g][3][2], st[g][3][3]));
      tm[g] = fmaxf(fmaxf(t0, t1), fmaxf(t2, t3));
    }
    if (__any(tm[0] > m_i[0] || tm[1] > m_i[1])) {
#pragma unroll
      for (int g = 0; g < 2; ++g) {
        float tr = tm[g];
        tr = fmaxf(tr, __shfl_xor(tr, 16));
        tr = fmaxf(tr, __shfl_xor(tr, 32));
        const float m_new = (tr > m_i[g]) ? tr + 5.0f : m_i[g];
        const float alpha = exp2f(m_i[g] - m_new);
        m_i[g] = m_new;
        l_p[g] *= alpha;
        float a4[4];
#pragma unroll
        for (int r = 0; r < 4; ++r) a4[r] = __shfl(alpha, qd * 4 + r);
#pragma unroll
        for (int ct = 0; ct < 16; ++ct)
#pragma unroll
          for (int r = 0; r < 4; ++r) acc[g][ct][r] *= a4[r];
      }
    }

#pragma unroll
    for (int g = 0; g < 2; ++g) {
      float ts = 0.f;
#pragma unroll
      for (int a = 0; a < 4; ++a) {
        half4 h;
#pragma unroll
        for (int r = 0; r < 4; ++r) {
          const float p = exp2f(st[g][a][r] - m_i[g]);
          ts += p;
          h[r] = (f16)p;
        }
        const int pc = ((a * 2 + (qd >> 1)) ^ sx7) * 8 + (qd & 1) * 4;
        *(half4*)&ps[wid][g][c16 * 64 + pc] = h;
      }
      l_p[g] += ts;
    }

    __syncthreads();  // [A] drains vmcnt -> vsT(k0) landed everywhere

    const int k0n = (k0 + 64 < kend) ? (k0 + 64) : kbeg;
    half8 knew[4];
#pragma unroll
    for (int a = 0; a < 4; ++a)
      knew[a] = *(const half8*)(g_Kh + ((size_t)(b * NN + k0n + a * 16 + c16)) * ND + qd * 8);

    half8 pa[2][2];
#pragma unroll
    for (int g = 0; g < 2; ++g)
#pragma unroll
      for (int kh = 0; kh < 2; ++kh)
        pa[g][kh] = *(const half8*)&ps[wid][g][c16 * 64 + ((kh * 4 + qd) ^ sx7) * 8];
#pragma unroll
    for (int ct = 0; ct < 16; ++ct) {
#pragma unroll
      for (int kh = 0; kh < 2; ++kh) {
        const half8 bfr =
            *(const half8*)&vsT[(ct * 16 + c16) * 64 + ((kh * 4 + qd) ^ sx7) * 8];
        acc[0][ct] = MFMA_F16(pa[0][kh], bfr, acc[0][ct]);
        acc[1][ct] = MFMA_F16(pa[1][kh], bfr, acc[1][ct]);
      }
    }
    __syncthreads();  // [B] all waves done reading vsT(k0)

    if (k0 + 64 < kend) {
#pragma unroll
      for (int i = 0; i < 8; ++i)
        gl2lds16(vlane + (k0 + 64) + i * 8 * NN, vdst + i * 512);
    }
#pragma unroll
    for (int a = 0; a < 4; ++a) kreg[a] = knew[a];
  }

  // ---- write normalized partial + (m,l) ----
#pragma unroll
  for (int g = 0; g < 2; ++g) {
    float l = l_p[g];
    l += __shfl_xor(l, 16);
    l += __shfl_xor(l, 32);
    if (qd == 0) {
      const int row = b * NN + q0 + g * 16 + c16;
      g_m[s * PIX + row] = m_i[g];
      g_l[s * PIX + row] = l;
    }
    float linv[4];
#pragma unroll
    for (int r = 0; r < 4; ++r) linv[r] = 1.0f / __shfl(l, qd * 4 + r);
#pragma unroll
    for (int ct = 0; ct < 16; ++ct)
#pragma unroll
      for (int r = 0; r < 4; ++r) {
        const int qrow = q0 + g * 16 + qd * 4 + r;
        const int c = ct * 16 + c16;
        g_Of[((size_t)(s * PIX + b * NN + qrow)) * NC + c] = (f16)(acc[g][ct][r] * linv[r]);
      }
  }

  // ---- last-arriving block per q-tile merges all NS partials ----
  __threadfence();   // release: partial visible device-wide before counter bump
  __syncthreads();
  if (tid == 0) s_last = (atomicAdd(&g_cnt[b * (NN / 128) + blockIdx.x], 1) == NS - 1);
  __syncthreads();
  if (!s_last) return;
  __threadfence();   // acquire: see the other splits' partials

  const int rowbase = b * NN + blockIdx.x * 128;
  float* wbuf = (float*)ps;  // reuse 16 KB LDS: [s][128] normalized weights
  if (tid < 128) {
    const int row = rowbase + tid;
    float mm[NS], ll[NS], M = -1e30f;
#pragma unroll
    for (int si = 0; si < NS; ++si) {
      mm[si] = g_m[si * PIX + row];
      ll[si] = g_l[si * PIX + row];
      M = fmaxf(M, mm[si]);
    }
    float den = 0.f, w[NS];
#pragma unroll
    for (int si = 0; si < NS; ++si) { w[si] = ll[si] * exp2f(mm[si] - M); den += w[si]; }
    const float inv = 1.0f / den;
#pragma unroll
    for (int si = 0; si < NS; ++si) wbuf[si * 128 + tid] = w[si] * inv;
  }
  __syncthreads();

#pragma unroll
  for (int rr = 0; rr < 16; ++rr) {
    const int rl  = rr * 8 + (tid >> 5);        // local row 0..127
    const int row = rowbase + rl;
    const int ch  = (tid & 31) * 8;             // 32 thr x 8 ch = 256, coalesced
    float o[8] = {0.f, 0.f, 0.f, 0.f, 0.f, 0.f, 0.f, 0.f};
#pragma unroll
    for (int si = 0; si < NS; ++si) {
      const half8 h = *(const half8*)&g_Of[((size_t)(si * PIX + row)) * NC + ch];
      const float ws = wbuf[si * 128 + rl];     // LDS broadcast within row group
#pragma unroll
      for (int e = 0; e < 8; ++e) o[e] += ws * (float)h[e];
    }
    const half8 xv = *(const half8*)&g_Xh[(size_t)row * NC + ch];
    floatx4 o0, o1;
    o0[0] = o[0] + (float)xv[0]; o0[1] = o[1] + (float)xv[1];
    o0[2] = o[2] + (float)xv[2]; o0[3] = o[3] + (float)xv[3];
    o1[0] = o[4] + (float)xv[4]; o1[1] = o[5] + (float)xv[5];
    o1[2] = o[6] + (float)xv[6]; o1[3] = o[7] + (float)xv[7];
    *(floatx4*)&out[(size_t)row * NC + ch] = o0;
    *(floatx4*)&out[(size_t)row * NC + ch + 4] = o1;
  }
}

// ---------------------------------------------------------------------------
extern "C" void kernel_launch(void* const* d_in, const int* in_sizes, int n_in,
                              void* d_out, int out_size, void* d_ws, size_t ws_size,
                              hipStream_t stream) {
  (void)in_sizes; (void)n_in; (void)d_ws; (void)ws_size; (void)out_size;
  const float* x  = (const float*)d_in[0];
  const float* wq = (const float*)d_in[1];
  const float* bq = (const float*)d_in[2];
  const float* wk = (const float*)d_in[3];
  const float* bk = (const float*)d_in[4];
  const float* wv = (const float*)d_in[5];
  const float* bv = (const float*)d_in[6];
  float* out = (float*)d_out;

  hipLaunchKernelGGL(prep_weights, dim3(320), dim3(256), 0, stream, wq, wk, wv);
  hipLaunchKernelGGL(proj_qkv, dim3(256), dim3(256), 0, stream, x, bq, bk, bv);
  hipLaunchKernelGGL(attn_split, dim3(NN / 128, NB, NS), dim3(256), 0, stream, out);
}

// Round 10
// 168.734 us; speedup vs baseline: 1.6744x; 1.6744x over previous
//
#include <hip/hip_runtime.h>
#include <stdint.h>

typedef _Float16 f16;
typedef f16 half8 __attribute__((ext_vector_type(8)));
typedef f16 half4 __attribute__((ext_vector_type(4)));
typedef float floatx4 __attribute__((ext_vector_type(4)));

#define MFMA_F16(A, B, Cc) __builtin_amdgcn_mfma_f32_16x16x32_f16((A), (B), (Cc), 0, 0, 0)

// Problem constants: B=4, H=W=64 -> N=4096, C=256, d=32
static constexpr int NB  = 4;
static constexpr int NN  = 4096;
static constexpr int NC  = 256;
static constexpr int ND  = 32;
static constexpr int PIX = NB * NN;   // 16384
static constexpr int NS  = 4;         // key splits (grid 512 = 2 blocks/CU, reg-capped)
static constexpr int KS  = NN / NS;   // 1024 keys per split

// LDS K-stride for proj tiles: 264 halfs = 528 B (16B-aligned; 132 dwords
// == 4 mod 32 -> 2-way bank aliasing, free).
static constexpr int XP = 264;

// Device-global scratch. Fully rewritten every launch.
__device__ __align__(16) f16 g_Xh[(size_t)PIX * NC];        // x as f16 (proj side product)
__device__ __align__(16) f16 g_WbT[320 * 256];              // [j][k]
__device__ __align__(16) f16 g_Qh[(size_t)PIX * ND];        // [row][32], pre-scaled log2(e)
__device__ __align__(16) f16 g_Kh[(size_t)PIX * ND];        // [row][32]
__device__ __align__(16) f16 g_VbT[(size_t)NB * NC * NN];   // [b][c][n]
__device__ __align__(16) f16 g_Of[(size_t)NS * PIX * NC];   // per-split normalized O
__device__ float g_m[NS * PIX];                             // per-split max (log2 dom)
__device__ float g_l[NS * PIX];                             // per-split denom

__device__ inline void gl2lds16(const f16* g, f16* l) {
  __builtin_amdgcn_global_load_lds(
      (const __attribute__((address_space(1))) void*)g,
      (__attribute__((address_space(3))) void*)l, 16, 0, 0);
}

// ---------------------------------------------------------------------------
__global__ __launch_bounds__(256) void prep_weights(const float* __restrict__ wq,
                                                    const float* __restrict__ wk,
                                                    const float* __restrict__ wv) {
  const int tid = blockIdx.x * 256 + threadIdx.x;
  if (tid >= 320 * 256) return;
  const int j = tid >> 8;
  const int k = tid & 255;
  float v;
  if (j < 32)      v = wq[k * 32 + j];
  else if (j < 64) v = wk[k * 32 + (j - 32)];
  else             v = wv[k * 256 + (j - 64)];
  g_WbT[j * 256 + k] = (f16)v;
}

// ---------------------------------------------------------------------------
// QKV projection v3: 512 blocks x 32 rows (2 blocks/CU). x-tile staged ONCE
// (fp32 read once; f16 side-written to g_Xh for combine's residual), then 5
// j-chunks each staging the FULL 64x256 W-chunk once -- the K-loop runs
// entirely from LDS (round-6/9 proj re-staged W every K-step at 1 block/CU
// and measured ~75 us).
__global__ __launch_bounds__(256) void proj_qkv(const float* __restrict__ x,
                                                const float* __restrict__ bq,
                                                const float* __restrict__ bk,
                                                const float* __restrict__ bv) {
  __shared__ f16 xs[32 * XP];   // 16896 B [row][k]
  __shared__ f16 ws[64 * XP];   // 33792 B [j][k]; vt (64x32) aliases its head
  f16* vt = ws;

  const int tid  = threadIdx.x;
  const int lane = tid & 63;
  const int wid  = tid >> 6;
  const int qd   = lane >> 4;
  const int c16  = lane & 15;
  const int p0   = blockIdx.x * 32;
  const int b    = p0 >> 12;
  const int n0   = p0 & (NN - 1);
  const floatx4 zero4 = {0.f, 0.f, 0.f, 0.f};

  // ---- stage x tile once: 32 rows x 256 cols fp32 -> f16 (+ g_Xh) ----
  {
    const int r = tid >> 3, g = tid & 7;  // 8 threads/row, 32 consecutive floats each
    const floatx4* src = (const floatx4*)(x + (size_t)(p0 + r) * NC + g * 32);
#pragma unroll
    for (int i = 0; i < 4; ++i) {
      const floatx4 va = src[i * 2], vb = src[i * 2 + 1];
      half8 h;
      h[0] = (f16)va[0]; h[1] = (f16)va[1]; h[2] = (f16)va[2]; h[3] = (f16)va[3];
      h[4] = (f16)vb[0]; h[5] = (f16)vb[1]; h[6] = (f16)vb[2]; h[7] = (f16)vb[3];
      *(half8*)&xs[r * XP + g * 32 + i * 8] = h;
      *(half8*)&g_Xh[(size_t)(p0 + r) * NC + g * 32 + i * 8] = h;
    }
  }

  for (int ch = 0; ch < 5; ++ch) {
    __syncthreads();  // prev chunk's vt reads done (vt aliases ws); xs staged (ch 0)
    // ---- stage W chunk: 64 j x 256 k (f16, L2-resident) ----
    {
      const int jj = tid >> 2, g = tid & 3;  // 4 threads/j, 64 halfs each
#pragma unroll
      for (int i = 0; i < 8; ++i)
        *(half8*)&ws[jj * XP + g * 64 + i * 8] =
            *(const half8*)&g_WbT[(size_t)(ch * 64 + jj) * 256 + g * 64 + i * 8];
    }
    __syncthreads();

    // ---- compute: wave wid -> j-tile wid; 2 row-tiles; K from LDS ----
    floatx4 acc2[2] = {zero4, zero4};
    for (int kk = 0; kk < 256; kk += 32) {
      const half8 bfr = *(const half8*)&ws[(wid * 16 + c16) * XP + kk + qd * 8];
#pragma unroll
      for (int rt = 0; rt < 2; ++rt) {
        const half8 a = *(const half8*)&xs[(rt * 16 + c16) * XP + kk + qd * 8];
        acc2[rt] = MFMA_F16(a, bfr, acc2[rt]);
      }
    }

    if (ch == 0) {
      const int j = wid * 16 + c16;  // 0..63: Q then K
      const float bias = (j < 32) ? bq[j] : bk[j - 32];
#pragma unroll
      for (int rt = 0; rt < 2; ++rt)
#pragma unroll
        for (int r = 0; r < 4; ++r) {
          const int p = p0 + rt * 16 + qd * 4 + r;
          const float val = acc2[rt][r] + bias;
          if (j < 32) g_Qh[(size_t)p * ND + j] = (f16)(val * 1.44269504f);
          else        g_Kh[(size_t)p * ND + (j - 32)] = (f16)val;
        }
    } else {
      const int cl = wid * 16 + c16;  // channel-local 0..63
      const float bias = bv[(ch - 1) * 64 + cl];
      half4 h0, h1;
#pragma unroll
      for (int r = 0; r < 4; ++r) {
        h0[r] = (f16)(acc2[0][r] + bias);
        h1[r] = (f16)(acc2[1][r] + bias);
      }
      __syncthreads();  // all ws MFMA reads done before vt overwrite
      *(half4*)&vt[cl * 32 + qd * 4] = h0;
      *(half4*)&vt[cl * 32 + 16 + qd * 4] = h1;
      __syncthreads();
      // coalesced V^T store: 64 ch x 32 keys
      const int c = tid >> 2, part = tid & 3;
      *(half8*)(g_VbT + ((size_t)(b * NC + (ch - 1) * 64 + c)) * NN + n0 + part * 8) =
          *(const half8*)&vt[c * 32 + part * 8];
    }
  }
}

// ---------------------------------------------------------------------------
// Flash attention (round-6 core verbatim, measured 70 us): block = 128 q
// (4 waves x 32 q), K-tile = 64 keys, blockIdx.z = 1024-key split. K direct
// from global into regs; V async gl2lds into XOR-chunk-swizzled vsT.
__global__ __launch_bounds__(256, 2) void attn_split(void) {
  __shared__ f16 vsT[256 * 64];        // 32 KB [c][64 keys], chunk-swizzled
  __shared__ f16 ps[4][2][16 * 64];    // 16 KB [wave][qgrp][q][64 keys], swizzled

  const int tid  = threadIdx.x;
  const int lane = tid & 63;
  const int wid  = tid >> 6;
  const int qd   = lane >> 4;
  const int c16  = lane & 15;
  const int b    = blockIdx.y;
  const int s    = blockIdx.z;
  const int q0   = blockIdx.x * 128 + wid * 32;
  const int sx7  = c16 & 7;
  const floatx4 zero4 = {0.f, 0.f, 0.f, 0.f};

  const int vrow = wid * 64 + (lane >> 3);
  const int vchk = (lane & 7) ^ ((lane >> 3) & 7);
  const f16* vlane = g_VbT + ((size_t)(b * NC + vrow)) * NN + vchk * 8;
  f16* vdst = &vsT[(size_t)wid * 4096];

  half8 qf[2];
#pragma unroll
  for (int g = 0; g < 2; ++g)
    qf[g] = *(const half8*)(g_Qh + ((size_t)(b * NN + q0 + g * 16 + c16)) * ND + qd * 8);

  floatx4 acc[2][16];
#pragma unroll
  for (int g = 0; g < 2; ++g)
#pragma unroll
    for (int i = 0; i < 16; ++i) acc[g][i] = zero4;
  float m_i[2] = {-1e30f, -1e30f};
  float l_p[2] = {0.f, 0.f};

  const int kbeg = s * KS, kend = (s + 1) * KS;

#pragma unroll
  for (int i = 0; i < 8; ++i)
    gl2lds16(vlane + kbeg + i * 8 * NN, vdst + i * 512);
  half8 kreg[4];
#pragma unroll
  for (int a = 0; a < 4; ++a)
    kreg[a] = *(const half8*)(g_Kh + ((size_t)(b * NN + kbeg + a * 16 + c16)) * ND + qd * 8);

  for (int k0 = kbeg; k0 < kend; k0 += 64) {
    floatx4 st[2][4];
#pragma unroll
    for (int g = 0; g < 2; ++g)
#pragma unroll
      for (int a = 0; a < 4; ++a) st[g][a] = MFMA_F16(kreg[a], qf[g], zero4);

    float tm[2];
#pragma unroll
    for (int g = 0; g < 2; ++g) {
      float t0 = fmaxf(fmaxf(st[g][0][0], st[g][0][1]), fmaxf(st[g][0][2], st[g][0][3]));
      float t1 = fmaxf(fmaxf(st[g][1][0], st[g][1][1]), fmaxf(st[g][1][2], st[g][1][3]));
      float t2 = fmaxf(fmaxf(st[g][2][0], st[g][2][1]), fmaxf(st[g][2][2], st[g][2][3]));
      float t3 = fmaxf(fmaxf(st[g][3][0], st[g][3][1]), fmaxf(st[g][3][2], st[g][3][3]));
      tm[g] = fmaxf(fmaxf(t0, t1), fmaxf(t2, t3));
    }
    if (__any(tm[0] > m_i[0] || tm[1] > m_i[1])) {
#pragma unroll
      for (int g = 0; g < 2; ++g) {
        float tr = tm[g];
        tr = fmaxf(tr, __shfl_xor(tr, 16));
        tr = fmaxf(tr, __shfl_xor(tr, 32));
        const float m_new = (tr > m_i[g]) ? tr + 5.0f : m_i[g];
        const float alpha = exp2f(m_i[g] - m_new);
        m_i[g] = m_new;
        l_p[g] *= alpha;
        float a4[4];
#pragma unroll
        for (int r = 0; r < 4; ++r) a4[r] = __shfl(alpha, qd * 4 + r);
#pragma unroll
        for (int ct = 0; ct < 16; ++ct)
#pragma unroll
          for (int r = 0; r < 4; ++r) acc[g][ct][r] *= a4[r];
      }
    }

#pragma unroll
    for (int g = 0; g < 2; ++g) {
      float ts = 0.f;
#pragma unroll
      for (int a = 0; a < 4; ++a) {
        half4 h;
#pragma unroll
        for (int r = 0; r < 4; ++r) {
          const float p = exp2f(st[g][a][r] - m_i[g]);
          ts += p;
          h[r] = (f16)p;
        }
        const int pc = ((a * 2 + (qd >> 1)) ^ sx7) * 8 + (qd & 1) * 4;
        *(half4*)&ps[wid][g][c16 * 64 + pc] = h;
      }
      l_p[g] += ts;
    }

    __syncthreads();  // [A] drains vmcnt -> vsT(k0) landed everywhere

    const int k0n = (k0 + 64 < kend) ? (k0 + 64) : kbeg;
    half8 knew[4];
#pragma unroll
    for (int a = 0; a < 4; ++a)
      knew[a] = *(const half8*)(g_Kh + ((size_t)(b * NN + k0n + a * 16 + c16)) * ND + qd * 8);

    half8 pa[2][2];
#pragma unroll
    for (int g = 0; g < 2; ++g)
#pragma unroll
      for (int kh = 0; kh < 2; ++kh)
        pa[g][kh] = *(const half8*)&ps[wid][g][c16 * 64 + ((kh * 4 + qd) ^ sx7) * 8];
#pragma unroll
    for (int ct = 0; ct < 16; ++ct) {
#pragma unroll
      for (int kh = 0; kh < 2; ++kh) {
        const half8 bfr =
            *(const half8*)&vsT[(ct * 16 + c16) * 64 + ((kh * 4 + qd) ^ sx7) * 8];
        acc[0][ct] = MFMA_F16(pa[0][kh], bfr, acc[0][ct]);
        acc[1][ct] = MFMA_F16(pa[1][kh], bfr, acc[1][ct]);
      }
    }
    __syncthreads();  // [B] all waves done reading vsT(k0)

    if (k0 + 64 < kend) {
#pragma unroll
      for (int i = 0; i < 8; ++i)
        gl2lds16(vlane + (k0 + 64) + i * 8 * NN, vdst + i * 512);
    }
#pragma unroll
    for (int a = 0; a < 4; ++a) kreg[a] = knew[a];
  }

  // ---- epilogue: normalized partial + (m,l) ----
#pragma unroll
  for (int g = 0; g < 2; ++g) {
    float l = l_p[g];
    l += __shfl_xor(l, 16);
    l += __shfl_xor(l, 32);
    if (qd == 0) {
      const int row = b * NN + q0 + g * 16 + c16;
      g_m[s * PIX + row] = m_i[g];
      g_l[s * PIX + row] = l;
    }
    float linv[4];
#pragma unroll
    for (int r = 0; r < 4; ++r) linv[r] = 1.0f / __shfl(l, qd * 4 + r);
#pragma unroll
    for (int ct = 0; ct < 16; ++ct)
#pragma unroll
      for (int r = 0; r < 4; ++r) {
        const int qrow = q0 + g * 16 + qd * 4 + r;
        const int c = ct * 16 + c16;
        g_Of[((size_t)(s * PIX + b * NN + qrow)) * NC + c] = (f16)(acc[g][ct][r] * linv[r]);
      }
  }
}

// ---------------------------------------------------------------------------
// Merge NS partials (log2 domain); residual from g_Xh (f16). Separate kernel
// on purpose: round 9's fused last-block merge serialized on 1/4 of the CUs
// and regressed attn 79 -> 200 us.
__global__ __launch_bounds__(256) void combine(float* __restrict__ out) {
  const int tid  = threadIdx.x;
  const int lane = tid & 63;
  const int wid  = tid >> 6;
  const int row  = blockIdx.x * 4 + wid;
  const int c    = lane * 4;

  float m[NS], l[NS], M = -1e30f;
#pragma unroll
  for (int s = 0; s < NS; ++s) {
    m[s] = g_m[s * PIX + row];
    l[s] = g_l[s * PIX + row];
    M = fmaxf(M, m[s]);
  }
  float w[NS], den = 0.f;
#pragma unroll
  for (int s = 0; s < NS; ++s) { w[s] = l[s] * exp2f(m[s] - M); den += w[s]; }
  const float inv = 1.0f / den;

  float a0 = 0.f, a1 = 0.f, a2 = 0.f, a3 = 0.f;
#pragma unroll
  for (int s = 0; s < NS; ++s) {
    const half4 h = *(const half4*)&g_Of[((size_t)(s * PIX + row)) * NC + c];
    const float ws = w[s] * inv;
    a0 += ws * (float)h[0];
    a1 += ws * (float)h[1];
    a2 += ws * (float)h[2];
    a3 += ws * (float)h[3];
  }
  const half4 xv = *(const half4*)&g_Xh[(size_t)row * NC + c];
  floatx4 o;
  o[0] = a0 + (float)xv[0]; o[1] = a1 + (float)xv[1];
  o[2] = a2 + (float)xv[2]; o[3] = a3 + (float)xv[3];
  *(floatx4*)&out[(size_t)row * NC + c] = o;
}

// ---------------------------------------------------------------------------
extern "C" void kernel_launch(void* const* d_in, const int* in_sizes, int n_in,
                              void* d_out, int out_size, void* d_ws, size_t ws_size,
                              hipStream_t stream) {
  (void)in_sizes; (void)n_in; (void)d_ws; (void)ws_size; (void)out_size;
  const float* x  = (const float*)d_in[0];
  const float* wq = (const float*)d_in[1];
  const float* bq = (const float*)d_in[2];
  const float* wk = (const float*)d_in[3];
  const float* bk = (const float*)d_in[4];
  const float* wv = (const float*)d_in[5];
  const float* bv = (const float*)d_in[6];
  float* out = (float*)d_out;

  hipLaunchKernelGGL(prep_weights, dim3(320), dim3(256), 0, stream, wq, wk, wv);
  hipLaunchKernelGGL(proj_qkv, dim3(PIX / 32), dim3(256), 0, stream, x, bq, bk, bv);
  hipLaunchKernelGGL(attn_split, dim3(NN / 128, NB, NS), dim3(256), 0, stream);
  hipLaunchKernelGGL(combine, dim3(PIX / 4), dim3(256), 0, stream, out);
}